// Round 15
// baseline (262.756 us; speedup 1.0000x reference)
//
#include <hip/hip_runtime.h>
#include <hip/hip_bf16.h>

typedef unsigned short u16;
typedef __attribute__((ext_vector_type(4))) short bf16x4;
typedef __attribute__((ext_vector_type(8))) short bf16x8;
typedef __attribute__((ext_vector_type(4))) float f32x4;

// ---------- helpers ----------
static __device__ __forceinline__ u16 f2b(float f){
  union { float f; unsigned u; } v; v.f = f;
  unsigned r = v.u + 0x7fffu + ((v.u >> 16) & 1u);   // RNE
  return (u16)(r >> 16);
}
static __device__ __forceinline__ float b2f(u16 h){
  union { unsigned u; float f; } v; v.u = ((unsigned)h) << 16; return v.f;
}
static __device__ __forceinline__ void gld_lds16(const void* g, void* l){
  __builtin_amdgcn_global_load_lds((const __attribute__((address_space(1))) void*)g,
                                   (__attribute__((address_space(3))) void*)l, 16, 0, 0);
}

// ---------- prep: Q/K bf16 convert (8 rows/block) + Wq/Wk/Wv transposes ----------
__global__ __launch_bounds__(256) void prep(const float* __restrict__ Q,
                                            const float* __restrict__ K,
                                            u16* __restrict__ Qb, u16* __restrict__ Kb,
                                            const float* __restrict__ Wq, u16* __restrict__ Wq_t,
                                            const float* __restrict__ Wk, u16* __restrict__ Wk_t,
                                            const float* __restrict__ Wv, u16* __restrict__ Wv_t){
  __shared__ float tile[64][65];
  const int id = blockIdx.x, t = threadIdx.x;
  if (id < 1024){
#pragma unroll
    for (int i = 0; i < 8; i++){
      int row = id * 8 + i;                 // 0..8191; blocks never straddle 4096
      const float* src; u16* dst;
      if (row < 4096){
        src = Q + (size_t)row * 1024; dst = Qb + (size_t)row * 1024;
      } else {
        int r = row - 4096;
        size_t ir = (size_t)r + (size_t)(r >> 10) * 512;   // skip rows 1024..1535 per batch
        src = K + ir * 1024; dst = Kb + (size_t)r * 1024;
      }
      const float4 v = *(const float4*)(src + t * 4);
      bf16x4 o;
      o[0] = (short)f2b(v.x); o[1] = (short)f2b(v.y);
      o[2] = (short)f2b(v.z); o[3] = (short)f2b(v.w);
      *(bf16x4*)(dst + t * 4) = o;
    }
    return;
  }
  int wid = id - 1024;               // 0..767 : 3 x 256 tiles (Wq, Wk, Wv)
  int sel = wid >> 8, local = wid & 255;
  int bx = local & 15, by = local >> 4;
  const float* in  = (sel == 0) ? Wq   : (sel == 1) ? Wk   : Wv;
  u16*         out = (sel == 0) ? Wq_t : (sel == 1) ? Wk_t : Wv_t;
  const int k0 = by * 64, n0 = bx * 64;
  const int tr = t >> 4, tc = t & 15;
#pragma unroll
  for (int i = 0; i < 4; i++){
    int r = tr + i * 16;
    float4 v = *(const float4*)(in + (size_t)(k0 + r) * 1024 + n0 + tc * 4);
    tile[r][tc*4+0] = v.x; tile[r][tc*4+1] = v.y; tile[r][tc*4+2] = v.z; tile[r][tc*4+3] = v.w;
  }
  __syncthreads();
#pragma unroll
  for (int i = 0; i < 4; i++){
    int nr = tr + i * 16;
    bf16x4 pk;
#pragma unroll
    for (int j = 0; j < 4; j++) pk[j] = (short)f2b(tile[tc*4+j][nr]);
    *(bf16x4*)(out + (size_t)(n0 + nr) * 1024 + k0 + tc * 4) = pk;
  }
}

// ---------- 256x256 8-phase main loop; SWAP=1 computes C^T fragments (mfma(b,a)) ----------
// ks outermost in the MFMA cluster: 8 independent MFMAs between same-acc reuse
// (identical numerics: each acc still accumulates ks=0 then ks=1).
template<int SWAP>
static __device__ __forceinline__ void loop8p(const u16* __restrict__ A,
                                              const u16* __restrict__ Bt,
                                              int lda, int ldb, int kbeg, int NT,
                                              int m0, int n0,
                                              u16 (*sA)[2][8192], u16 (*sB)[2][8192],
                                              f32x4 acc[8][4]){
  const int t = threadIdx.x, w = t >> 6, l = t & 63;
  const int wr = w >> 2, wc = w & 3;
  const int c = l & 15, g = l >> 4;
  const int sr = t >> 3, scb = (t & 7) << 4;

  auto stA = [&](int d, int h, int T){
#pragma unroll
    for (int i = 0; i < 2; i++){
      int row = i * 64 + sr;
      int Lb  = scb ^ ((row & 7) << 4);
      gld_lds16(A + (size_t)(m0 + h * 128 + row) * lda + kbeg + T * 64 + (Lb >> 1),
                (char*)&sA[d][h][0] + i * 8192 + t * 16);
    }
  };
  auto stB = [&](int d, int h, int T){
#pragma unroll
    for (int i = 0; i < 2; i++){
      int row = i * 64 + sr;
      int Lb  = scb ^ ((row & 7) << 4);
      gld_lds16(Bt + (size_t)(n0 + h * 128 + row) * ldb + kbeg + T * 64 + (Lb >> 1),
                (char*)&sB[d][h][0] + i * 8192 + t * 16);
    }
  };

  // prologue: B0(0),B1(0),A0(0),A1(0),B0(1),B1(1)
  stB(0, 0, 0); stB(0, 1, 0); stA(0, 0, 0); stA(0, 1, 0);
  stB(1, 0, 1); stB(1, 1, 1);

  bf16x8 bfr[4][2];
  for (int T = 0; T < NT; ++T){
    const int d = T & 1;
    const char* pa = (const char*)&sA[d][wr][0];
    const char* pb = (const char*)&sB[d][wc >> 1][0];
#pragma unroll
    for (int q = 0; q < 4; ++q){
      if (q == 0){
        if (T + 1 < NT) asm volatile("s_waitcnt vmcnt(4)" ::: "memory");
        else            asm volatile("s_waitcnt vmcnt(0)" ::: "memory");
        asm volatile("" ::: "memory");
        __builtin_amdgcn_s_barrier();
        asm volatile("" ::: "memory");
#pragma unroll
        for (int nf = 0; nf < 4; ++nf){
          int lr = (wc & 1) * 64 + nf * 16 + c;
#pragma unroll
          for (int ks = 0; ks < 2; ++ks)
            bfr[nf][ks] = *(const bf16x8*)(pb + lr * 128 + ((ks * 64 + g * 16) ^ ((lr & 7) << 4)));
        }
      }
      bf16x8 af[2][2];
#pragma unroll
      for (int mi = 0; mi < 2; ++mi){
        int lr = (q * 2 + mi) * 16 + c;
#pragma unroll
        for (int ks = 0; ks < 2; ++ks)
          af[mi][ks] = *(const bf16x8*)(pa + lr * 128 + ((ks * 64 + g * 16) ^ ((lr & 7) << 4)));
      }
      if      (q == 0){ if (T + 1 < NT) stA(d ^ 1, 0, T + 1); }
      else if (q == 1){ if (T + 1 < NT) stA(d ^ 1, 1, T + 1); }
      else if (q == 2){ if (T + 2 < NT) stB(d, 0, T + 2); }
      else            { if (T + 2 < NT) stB(d, 1, T + 2); }
      __builtin_amdgcn_s_setprio(1);
#pragma unroll
      for (int ks = 0; ks < 2; ++ks)
#pragma unroll
        for (int mi = 0; mi < 2; ++mi)
#pragma unroll
          for (int nf = 0; nf < 4; ++nf)
            acc[q * 2 + mi][nf] = SWAP
              ? __builtin_amdgcn_mfma_f32_16x16x32_bf16(bfr[nf][ks], af[mi][ks], acc[q * 2 + mi][nf], 0, 0, 0)
              : __builtin_amdgcn_mfma_f32_16x16x32_bf16(af[mi][ks], bfr[nf][ks], acc[q * 2 + mi][nf], 0, 0, 0);
      __builtin_amdgcn_s_setprio(0);
      asm volatile("" ::: "memory");
      __builtin_amdgcn_s_barrier();
      asm volatile("" ::: "memory");
    }
  }
}

// ---------- LDS-staged coalesced epilogue (unswapped layout; used by QKV q/k path) ----------
template<typename F>
static __device__ __forceinline__ void epi_store(char* sl, u16* gbase, int ld,
                                                 int l, F val){
  const int c = l & 15, g = l >> 4;
#pragma unroll
  for (int p = 0; p < 2; ++p){
#pragma unroll
    for (int mi = 0; mi < 4; ++mi){
#pragma unroll
      for (int nf = 0; nf < 4; ++nf){
        int col2 = (nf * 16 + c) * 2;
#pragma unroll
        for (int r = 0; r < 4; ++r){
          int row = mi * 16 + 4 * g + r;
          *(u16*)(sl + row * 128 + (col2 ^ ((row & 7) << 4))) = f2b(val(p * 4 + mi, nf, r));
        }
      }
    }
    asm volatile("s_waitcnt lgkmcnt(0)" ::: "memory");
    __builtin_amdgcn_sched_barrier(0);
#pragma unroll
    for (int j = 0; j < 8; ++j){
      int row = (l >> 3) + j * 8;
      int ch  = (l & 7) * 16;
      bf16x8 v = *(const bf16x8*)(sl + row * 128 + (ch ^ ((row & 7) << 4)));
      *(bf16x8*)(gbase + (size_t)(p * 64 + row) * ld + (l & 7) * 8) = v;
    }
    __builtin_amdgcn_sched_barrier(0);
  }
}

// ---------- 8-phase GEMM, SWAPPED operands -> direct bf16x4 stores (no LDS epilogue) ----------
// acc[mf][nf][r] = C[m0+wr*128+mf*16+c][n0+wc*64+nf*16+4g+r]
// EPI 0 (FF1, grid 16x16): bias+relu -> bf16. EPI 1 (grid 4x16x4): bf16 split-K partial.
template<int EPI>
__global__ __launch_bounds__(512, 2) void gemm8p(const u16* __restrict__ A,
                                                 const u16* __restrict__ Bt,
                                                 const float* __restrict__ bias,
                                                 void* __restrict__ outp,
                                                 int lda, int ldb, int ldout,
                                                 int ksz, int NT){
  __shared__ u16 sA[2][2][8192];
  __shared__ u16 sB[2][2][8192];
  const int t = threadIdx.x, w = t >> 6, l = t & 63;
  const int wr = w >> 2, wc = w & 3;
  const int c = l & 15, g = l >> 4;

  int m0, n0, zidx;
  if (EPI == 0){
    int lid = blockIdx.x + (blockIdx.y << 4);
    int xcd = lid & 7, slot = lid >> 3;
    int bx = ((xcd & 1) << 3) + (slot & 7);
    int by = ((xcd >> 1) << 2) + (slot >> 3);
    m0 = by * 256; n0 = bx * 256; zidx = 0;
  } else {
    int lid = blockIdx.x + (blockIdx.y << 2) + (blockIdx.z << 6);
    int xcd = lid & 7, slot = lid >> 3;
    int bx = slot & 3, rest = slot >> 2;
    int by = (xcd << 1) + (rest & 1);
    zidx = rest >> 1;
    m0 = by * 256; n0 = bx * 256;
  }

  f32x4 acc[8][4];
#pragma unroll
  for (int i = 0; i < 8; i++)
#pragma unroll
    for (int j = 0; j < 4; j++) acc[i][j] = (f32x4){0.f, 0.f, 0.f, 0.f};

  loop8p<1>(A, Bt, lda, ldb, zidx * ksz, NT, m0, n0, sA, sB, acc);

  const int mb = m0 + wr * 128 + c;
  const int nb = n0 + wc * 64 + 4 * g;
  if (EPI == 0){
    float4 bv4[4];
#pragma unroll
    for (int nf = 0; nf < 4; ++nf) bv4[nf] = *(const float4*)(bias + nb + nf * 16);
    u16* ob_ = (u16*)outp;
#pragma unroll
    for (int mf = 0; mf < 8; ++mf)
#pragma unroll
      for (int nf = 0; nf < 4; ++nf){
        bf16x4 pk;
        pk[0] = (short)f2b(fmaxf(acc[mf][nf][0] + bv4[nf].x, 0.f));
        pk[1] = (short)f2b(fmaxf(acc[mf][nf][1] + bv4[nf].y, 0.f));
        pk[2] = (short)f2b(fmaxf(acc[mf][nf][2] + bv4[nf].z, 0.f));
        pk[3] = (short)f2b(fmaxf(acc[mf][nf][3] + bv4[nf].w, 0.f));
        *(bf16x4*)(ob_ + (size_t)(mb + mf * 16) * ldout + nb + nf * 16) = pk;
      }
  } else {
    u16* po = (u16*)outp + (size_t)zidx * (4096ull * 1024ull);
#pragma unroll
    for (int mf = 0; mf < 8; ++mf)
#pragma unroll
      for (int nf = 0; nf < 4; ++nf){
        bf16x4 pk;
#pragma unroll
        for (int r = 0; r < 4; ++r) pk[r] = (short)f2b(acc[mf][nf][r]);
        *(bf16x4*)(po + (size_t)(mb + mf * 16) * 1024 + nb + nf * 16) = pk;
      }
  }
}

// ---------- fused QKV (blocks 0..191: GEMM, unswapped; 192..1343: Wo0/Wo/Wo2 transposes) ----------
__global__ __launch_bounds__(512, 2) void gemm8p_qkv(const u16* __restrict__ Qb,
                                                     const u16* __restrict__ Kb,
                                                     const u16* __restrict__ Wq_t,
                                                     const u16* __restrict__ Wk_t,
                                                     const u16* __restrict__ Wv_t,
                                                     const float* __restrict__ bq,
                                                     const float* __restrict__ bk,
                                                     const float* __restrict__ bv,
                                                     u16* __restrict__ qb,
                                                     u16* __restrict__ kbf,
                                                     u16* __restrict__ vtb,
                                                     const float* __restrict__ Wo0, u16* __restrict__ Wo0_t,
                                                     const float* __restrict__ Wo,  u16* __restrict__ Wo_t,
                                                     const float* __restrict__ Wo2, u16* __restrict__ Wo2_t){
  __shared__ u16 sA[2][2][8192];
  __shared__ u16 sB[2][2][8192];
  const int id = blockIdx.x, t = threadIdx.x;

  if (id >= 192){
    const int half = t >> 8, tt = t & 255;
    const int tileid = (id - 192) * 2 + half;          // 0..2303
    const float* in; u16* out; int Kd, N, bx, by;
    if (tileid < 256){
      bx = tileid & 15; by = tileid >> 4; Kd = 1024; N = 1024; in = Wo0; out = Wo0_t;
    } else if (tileid < 1280){
      int lo = tileid - 256; bx = lo & 63; by = lo >> 6; Kd = 1024; N = 4096; in = Wo; out = Wo_t;
    } else {
      int lo = tileid - 1280; bx = lo & 15; by = lo >> 4; Kd = 4096; N = 1024; in = Wo2; out = Wo2_t;
    }
    u16* tl = (u16*)&sA[0][0][0] + half * 4160;        // 64x65 u16 per half
    const int k0 = by * 64, n0 = bx * 64;
    const int tr = tt >> 4, tc = tt & 15;
#pragma unroll
    for (int i = 0; i < 4; i++){
      int r = tr + i * 16;
      float4 v = *(const float4*)(in + (size_t)(k0 + r) * N + n0 + tc * 4);
      tl[r * 65 + tc * 4 + 0] = f2b(v.x); tl[r * 65 + tc * 4 + 1] = f2b(v.y);
      tl[r * 65 + tc * 4 + 2] = f2b(v.z); tl[r * 65 + tc * 4 + 3] = f2b(v.w);
    }
    __syncthreads();
#pragma unroll
    for (int i = 0; i < 4; i++){
      int nr = tr + i * 16;
      bf16x4 pk;
#pragma unroll
      for (int j = 0; j < 4; j++) pk[j] = (short)tl[(tc * 4 + j) * 65 + nr];
      *(bf16x4*)(out + (size_t)(n0 + nr) * Kd + k0 + tc * 4) = pk;
    }
    return;
  }

  int lid = id;
  int xcd = lid & 7, slot = lid >> 3;
  int bx = (xcd & 3) * 3 + slot % 3;
  int by = ((xcd >> 2) << 3) + slot / 3;
  const int sel = bx >> 2;
  const u16* A    = sel ? Kb : Qb;
  const u16* Bt   = (sel == 0) ? Wq_t : (sel == 1) ? Wk_t : Wv_t;
  const float* bi = (sel == 0) ? bq   : (sel == 1) ? bk   : bv;
  const int w = t >> 6, l = t & 63;
  const int wr = w >> 2, wc = w & 3;
  const int c = l & 15, g = l >> 4;
  const int m0 = by * 256, n0 = (bx & 3) * 256;

  f32x4 acc[8][4];
#pragma unroll
  for (int i = 0; i < 8; i++)
#pragma unroll
    for (int j = 0; j < 4; j++) acc[i][j] = (f32x4){0.f, 0.f, 0.f, 0.f};

  loop8p<0>(A, Bt, 1024, 1024, 0, 16, m0, n0, sA, sB, acc);

  if (sel == 2){
    // V: per-wave LDS transpose (16KB slices), then coalesced vt row stores
    u16* sl = (w < 4) ? (&sA[0][0][0] + w * 8192) : (&sB[0][0][0] + (w - 4) * 8192);
#pragma unroll
    for (int nf = 0; nf < 4; ++nf){
      int n = n0 + wc * 64 + nf * 16 + c;
      float bv_ = bi[n];
#pragma unroll
      for (int mf = 0; mf < 8; ++mf){
        bf16x4 pk;
#pragma unroll
        for (int r = 0; r < 4; ++r) pk[r] = (short)f2b(acc[mf][nf][r] + bv_);
        *(bf16x4*)(sl + (nf * 16 + c) * 128 + mf * 16 + 4 * g) = pk;
      }
    }
    asm volatile("s_waitcnt lgkmcnt(0)" ::: "memory");
    __builtin_amdgcn_sched_barrier(0);
    const int mg = m0 + wr * 128;
    const int bb = mg >> 10, kb0 = mg & 1023;
    u16* vbase = vtb + ((size_t)bb << 20) + kb0;
#pragma unroll
    for (int j = 0; j < 16; ++j){
      int nl  = (l >> 4) + j * 4;
      int kl  = (l & 15) * 8;
      bf16x8 v = *(const bf16x8*)(sl + nl * 128 + kl);
      *(bf16x8*)(vbase + (size_t)(n0 + wc * 64 + nl) * 1024 + kl) = v;
    }
  } else {
    char* slw = (char*)&sA[0][0][0] + w * 8192;
    float bv[4];
#pragma unroll
    for (int nf = 0; nf < 4; ++nf) bv[nf] = bi[n0 + wc * 64 + nf * 16 + c];
    u16* out = sel ? kbf : qb;
    u16* gb  = out + (size_t)(m0 + wr * 128) * 1024 + n0 + wc * 64;
    epi_store(slw, gb, 1024, l,
              [&](int mf, int nf, int r){ return acc[mf][nf][r] + bv[nf]; });
  }
}

// ---------- combine NP bf16 partials + bias + residual, then LayerNorm ----------
template<int NP, int F32OUT>
__global__ __launch_bounds__(256) void comb_ln(const u16* __restrict__ pp,
                                               const float* __restrict__ bias,
                                               const u16* __restrict__ res,
                                               const float* __restrict__ gw,
                                               const float* __restrict__ bw,
                                               void* __restrict__ outp){
  const int t = threadIdx.x, w = t >> 6;
  const int row = blockIdx.x * 2 + (t >> 7);
  const int u = t & 127;
  const size_t i8 = (size_t)row * 1024 + u * 8;
  bf16x8 rv = *(const bf16x8*)(res + i8);
  float4 b0 = *(const float4*)(bias + u * 8);
  float4 b1 = *(const float4*)(bias + u * 8 + 4);
  float xs[8] = {b0.x, b0.y, b0.z, b0.w, b1.x, b1.y, b1.z, b1.w};
#pragma unroll
  for (int j = 0; j < 8; j++) xs[j] += b2f((u16)rv[j]);
#pragma unroll
  for (int z = 0; z < NP; z++){
    bf16x8 p = *(const bf16x8*)(pp + (size_t)z * (4096ull * 1024ull) + i8);
#pragma unroll
    for (int j = 0; j < 8; j++) xs[j] += b2f((u16)p[j]);
  }
  float s = 0.f, sq = 0.f;
#pragma unroll
  for (int j = 0; j < 8; j++){ s += xs[j]; sq += xs[j] * xs[j]; }
#pragma unroll
  for (int o = 32; o; o >>= 1){ s += __shfl_xor(s, o); sq += __shfl_xor(sq, o); }
  __shared__ float rs[4], rq[4];
  if ((t & 63) == 0){ rs[w] = s; rq[w] = sq; }
  __syncthreads();
  const int wb = (t >> 7) * 2;
  s  = rs[wb] + rs[wb + 1];
  sq = rq[wb] + rq[wb + 1];
  const float mu   = s * (1.f / 1024.f);
  const float var  = sq * (1.f / 1024.f) - mu * mu;
  const float rstd = rsqrtf(var + 1e-5f);
  float4 g0 = *(const float4*)(gw + u * 8);
  float4 g1 = *(const float4*)(gw + u * 8 + 4);
  float4 w0 = *(const float4*)(bw + u * 8);
  float4 w1 = *(const float4*)(bw + u * 8 + 4);
  float gv[8] = {g0.x, g0.y, g0.z, g0.w, g1.x, g1.y, g1.z, g1.w};
  float wv[8] = {w0.x, w0.y, w0.z, w0.w, w1.x, w1.y, w1.z, w1.w};
  if (F32OUT){
    float4 o0, o1;
    o0.x = (xs[0]-mu)*rstd*gv[0] + wv[0]; o0.y = (xs[1]-mu)*rstd*gv[1] + wv[1];
    o0.z = (xs[2]-mu)*rstd*gv[2] + wv[2]; o0.w = (xs[3]-mu)*rstd*gv[3] + wv[3];
    o1.x = (xs[4]-mu)*rstd*gv[4] + wv[4]; o1.y = (xs[5]-mu)*rstd*gv[5] + wv[5];
    o1.z = (xs[6]-mu)*rstd*gv[6] + wv[6]; o1.w = (xs[7]-mu)*rstd*gv[7] + wv[7];
    *(float4*)((float*)outp + i8)     = o0;
    *(float4*)((float*)outp + i8 + 4) = o1;
  } else {
    bf16x8 o;
#pragma unroll
    for (int j = 0; j < 8; j++) o[j] = (short)f2b((xs[j]-mu)*rstd*gv[j] + wv[j]);
    *(bf16x8*)((u16*)outp + i8) = o;
  }
}

// ---------- fused masked attention (128 q-rows/block, 8 waves) ----------
// QK: all ak0-MFMAs then all ak1-MFMAs (4-indep between same-st reuse).
// PV: nf outer, f inner (4-indep between same-acc reuse). Same accumulate order.
#define ATTN_STEP(IT, CUR, MC) do{                                              \
  if ((IT) < 15) asm volatile("s_waitcnt vmcnt(4)" ::: "memory");               \
  else           asm volatile("s_waitcnt vmcnt(0)" ::: "memory");               \
  __builtin_amdgcn_s_barrier();                                                 \
  asm volatile("" ::: "memory");                                                \
  if ((IT) < 15) stage((CUR) ^ 1, ((IT) + 1) * 64);                             \
  asm volatile("" ::: "memory");                                                \
  const char* kt = (const char*)sK[(CUR)];                                      \
  bf16x8 ak[4];                                                                 \
  f32x4 st[4];                                                                  \
  _Pragma("unroll")                                                             \
  for (int nf = 0; nf < 4; nf++)                                                \
    ak[nf] = *(const bf16x8*)(kt + (nf * 16 + c) * 128 + ((g * 16) ^ sw));      \
  _Pragma("unroll")                                                             \
  for (int nf = 0; nf < 4; nf++){                                               \
    f32x4 z = (f32x4){0.f, 0.f, 0.f, 0.f};                                      \
    st[nf] = __builtin_amdgcn_mfma_f32_16x16x32_bf16(ak[nf], bq0, z, 0, 0, 0);  \
  }                                                                             \
  _Pragma("unroll")                                                             \
  for (int nf = 0; nf < 4; nf++)                                                \
    ak[nf] = *(const bf16x8*)(kt + (nf * 16 + c) * 128 + ((64 + g * 16) ^ sw)); \
  _Pragma("unroll")                                                             \
  for (int nf = 0; nf < 4; nf++)                                                \
    st[nf] = __builtin_amdgcn_mfma_f32_16x16x32_bf16(ak[nf], bq1, st[nf], 0, 0, 0); \
  float rsum = 0.f;                                                             \
  bf16x4 pb[4];                                                                 \
  _Pragma("unroll")                                                             \
  for (int nf = 0; nf < 4; nf++)                                                \
    _Pragma("unroll")                                                           \
    for (int r = 0; r < 4; r++){                                                \
      float p = __expf(fmaf(st[nf][r], 0.03125f, MC[nf][r]) - 8.f);             \
      rsum += p;                                                                \
      pb[nf][r] = (short)f2b(p);                                                \
    }                                                                           \
  if ((IT) < 14){                                                               \
    _Pragma("unroll")                                                           \
    for (int nf = 0; nf < 4; nf++)                                              \
      MC[nf] = *(const f32x4*)(mbase + ((IT) + 2) * 64 + nf * 16 + g * 4);      \
  }                                                                             \
  rsum += __shfl_xor(rsum, 16); rsum += __shfl_xor(rsum, 32);                   \
  lsum += rsum;                                                                 \
  const char* vtc = (const char*)sV[(CUR)];                                     \
  __builtin_amdgcn_s_setprio(1);                                                \
  _Pragma("unroll")                                                             \
  for (int nf = 0; nf < 4; nf++){                                               \
    _Pragma("unroll")                                                           \
    for (int f = 0; f < 4; f++){                                                \
      const char* vr = vtc + (f * 16 + c) * 128;                                \
      bf16x4 av = *(const bf16x4*)(vr + ((nf * 32 + g * 8) ^ sw));              \
      acc[f] = __builtin_amdgcn_mfma_f32_16x16x16bf16_1k(av, pb[nf], acc[f], 0, 0, 0); \
    }                                                                           \
  }                                                                             \
  __builtin_amdgcn_s_setprio(0);                                                \
}while(0)

__global__ __launch_bounds__(512, 4) void attn_k(const u16* __restrict__ qb,
                                                 const u16* __restrict__ kb,
                                                 const u16* __restrict__ vt,
                                                 const float* __restrict__ mask,
                                                 u16* __restrict__ ob){
  __shared__ u16 sK[2][4096];   // [key 64][dh 64], row stride 128B, XOR-swizzled
  __shared__ u16 sV[2][4096];   // [dh 64][key 64], row stride 128B, XOR-swizzled

  const int aid = blockIdx.x, t = threadIdx.x;
  const int w = t >> 6, l = t & 63;
  const int c = l & 15, g = l >> 4;
  const int q0 = (aid & 7) * 128;
  const int h  = (aid >> 3) & 15, b = aid >> 7;
  const int qrow = q0 + w * 16 + c;
  const size_t qoff = ((size_t)(b * 1024 + qrow)) * 1024 + h * 64;
  const bf16x8 bq0 = *(const bf16x8*)(qb + qoff + g * 8);
  const bf16x8 bq1 = *(const bf16x8*)(qb + qoff + 32 + g * 8);
  const u16* kbase = kb + ((size_t)b * 1024) * 1024 + h * 64;
  const u16* vbase = vt + ((size_t)b << 20) + (size_t)(h * 64) * 1024;
  const float* mbase = mask + ((size_t)(h * 4 + b) * 1024 + qrow) * 1024;

  const int srow = t >> 3, slc = t & 7;             // 512 threads cover 64 rows x 128B

  auto stage = [&](int buf, int kv){
    int L = (slc * 16) ^ ((srow & 7) << 4);
    gld_lds16(kbase + (size_t)(kv + srow) * 1024 + (L >> 1), &sK[buf][t * 8]);
    gld_lds16(vbase + (size_t)srow * 1024 + kv + (L >> 1),   &sV[buf][t * 8]);
  };

  float lsum = 0.f;
  f32x4 acc[4];
#pragma unroll
  for (int f = 0; f < 4; f++) acc[f] = (f32x4){0.f, 0.f, 0.f, 0.f};

  stage(0, 0);
  asm volatile("" ::: "memory");
  f32x4 mA[4], mB[4];
#pragma unroll
  for (int nf = 0; nf < 4; nf++) mA[nf] = *(const f32x4*)(mbase + nf * 16 + g * 4);
  asm volatile("" ::: "memory");
#pragma unroll
  for (int nf = 0; nf < 4; nf++) mB[nf] = *(const f32x4*)(mbase + 64 + nf * 16 + g * 4);

  const int sw = (c & 7) << 4;
  for (int ii = 0; ii < 8; ++ii){
    ATTN_STEP(2 * ii,     0, mA);
    ATTN_STEP(2 * ii + 1, 1, mB);
  }

  // epilogue: barrier, O^T -> LDS, coalesced stores
  __syncthreads();
  const float inv = 1.f / lsum;
  u16* sO = &sK[0][0];                               // [128 rows][64 dh] = 16KB = all of sK
#pragma unroll
  for (int f = 0; f < 4; f++){
    bf16x4 pk;
#pragma unroll
    for (int r = 0; r < 4; r++) pk[r] = (short)f2b(acc[f][r] * inv);
    *(bf16x4*)(sO + (w * 16 + c) * 64 + f * 16 + 4 * g) = pk;
  }
  asm volatile("s_waitcnt lgkmcnt(0)" ::: "memory");
  __builtin_amdgcn_sched_barrier(0);
  {
    int rl  = w * 16 + (l >> 2);
    int d0  = (l & 3) * 16;
    bf16x8 v0 = *(const bf16x8*)(sO + rl * 64 + d0);
    bf16x8 v1 = *(const bf16x8*)(sO + rl * 64 + d0 + 8);
    u16* dst = ob + ((size_t)(b * 1024 + q0 + rl)) * 1024 + h * 64 + d0;
    *(bf16x8*)(dst)     = v0;
    *(bf16x8*)(dst + 8) = v1;
  }
}

// ---------- launch ----------
extern "C" void kernel_launch(void* const* d_in, const int* in_sizes, int n_in,
                              void* d_out, int out_size, void* d_ws, size_t ws_size,
                              hipStream_t stream){
  const float* Q    = (const float*)d_in[0];
  const float* K    = (const float*)d_in[1];
  const float* mask = (const float*)d_in[2];
  const float* Wq   = (const float*)d_in[4];  const float* bq  = (const float*)d_in[5];
  const float* Wk   = (const float*)d_in[6];  const float* bk  = (const float*)d_in[7];
  const float* Wv   = (const float*)d_in[8];  const float* bv  = (const float*)d_in[9];
  const float* Wo0  = (const float*)d_in[10]; const float* bo0 = (const float*)d_in[11];
  const float* Wo   = (const float*)d_in[12]; const float* bo  = (const float*)d_in[13];
  const float* Wo2  = (const float*)d_in[14]; const float* bo2 = (const float*)d_in[15];
  const float* g0   = (const float*)d_in[16]; const float* be0 = (const float*)d_in[17];
  const float* g1   = (const float*)d_in[18]; const float* be1 = (const float*)d_in[19];

  uint8_t* W = (uint8_t*)d_ws;
  const size_t MB = 1024ull * 1024ull;
  u16* Wq_t  = (u16*)(W + 0);
  u16* Wk_t  = (u16*)(W + 2  * MB);
  u16* Wv_t  = (u16*)(W + 4  * MB);
  u16* Wo0_t = (u16*)(W + 6  * MB);
  u16* Wo_t  = (u16*)(W + 8  * MB);   // [4096][1024]
  u16* Wo2_t = (u16*)(W + 16 * MB);   // [1024][4096]
  u16* Qb    = (u16*)(W + 24 * MB);
  u16* Kb    = (u16*)(W + 32 * MB);
  u16* qb    = (u16*)(W + 40 * MB);
  u16* kbf   = (u16*)(W + 48 * MB);
  u16* vtb   = (u16*)(W + 56 * MB);
  u16* ob    = (u16*)(W + 24 * MB);   // reuse Qb
  u16* x1b   = (u16*)(W + 64 * MB);
  u16* hb    = (u16*)(W + 32 * MB);   // [4096][4096] bf16, spans dead Kb/qb/kbf/vtb
  u16* ppb   = (u16*)(W + 72 * MB);   // 4 x 8MB bf16 split-K partials

  // Q/K convert (8 rows/block) + QKV weight transposes
  prep<<<1792, 256, 0, stream>>>(Q, K, Qb, Kb, Wq, Wq_t, Wk, Wk_t, Wv, Wv_t);

  // fused QKV projections (192 GEMM blocks) + 1152 transpose blocks (2304 tiles)
  gemm8p_qkv<<<1344, 512, 0, stream>>>(Qb, Kb, Wq_t, Wk_t, Wv_t,
                                       bq, bk, bv, qb, kbf, vtb,
                                       Wo0, Wo0_t, Wo, Wo_t, Wo2, Wo2_t);

  // attention (pure; 512 blocks x 512 threads)
  attn_k<<<512, 512, 0, stream>>>(qb, kbf, vtb, mask, ob);

  // output proj: 8-phase split-K=4 (NT=4), bf16 partials -> fused combine+LN0
  gemm8p<1><<<dim3(4, 16, 4), 512, 0, stream>>>(ob, Wo0_t, nullptr, ppb, 1024, 1024, 1024, 256, 4);
  comb_ln<4, 0><<<2048, 256, 0, stream>>>(ppb, bo0, qb, g0, be0, x1b);

  // FFN: FF1 (8-phase, relu) -> FF2 (8-phase, split-K=4, bf16 partials) -> combine+LN1
  gemm8p<0><<<dim3(16, 16), 512, 0, stream>>>(x1b, Wo_t, bo, hb, 1024, 1024, 4096, 0, 16);
  gemm8p<1><<<dim3(4, 16, 4), 512, 0, stream>>>(hb, Wo2_t, nullptr, ppb, 4096, 4096, 1024, 1024, 16);
  comb_ln<4, 1><<<2048, 256, 0, stream>>>(ppb, bo2, x1b, g1, be1, d_out);
}

// Round 16
// 257.739 us; speedup vs baseline: 1.0195x; 1.0195x over previous
//
#include <hip/hip_runtime.h>
#include <hip/hip_bf16.h>

typedef unsigned short u16;
typedef __attribute__((ext_vector_type(4))) short bf16x4;
typedef __attribute__((ext_vector_type(8))) short bf16x8;
typedef __attribute__((ext_vector_type(4))) float f32x4;

// ---------- helpers ----------
static __device__ __forceinline__ u16 f2b(float f){
  union { float f; unsigned u; } v; v.f = f;
  unsigned r = v.u + 0x7fffu + ((v.u >> 16) & 1u);   // RNE
  return (u16)(r >> 16);
}
static __device__ __forceinline__ float b2f(u16 h){
  union { unsigned u; float f; } v; v.u = ((unsigned)h) << 16; return v.f;
}
static __device__ __forceinline__ void gld_lds16(const void* g, void* l){
  __builtin_amdgcn_global_load_lds((const __attribute__((address_space(1))) void*)g,
                                   (__attribute__((address_space(3))) void*)l, 16, 0, 0);
}

// ---------- prep: Q/K bf16 convert (8 rows/block) + Wq/Wk/Wv transposes ----------
__global__ __launch_bounds__(256) void prep(const float* __restrict__ Q,
                                            const float* __restrict__ K,
                                            u16* __restrict__ Qb, u16* __restrict__ Kb,
                                            const float* __restrict__ Wq, u16* __restrict__ Wq_t,
                                            const float* __restrict__ Wk, u16* __restrict__ Wk_t,
                                            const float* __restrict__ Wv, u16* __restrict__ Wv_t){
  __shared__ float tile[64][65];
  const int id = blockIdx.x, t = threadIdx.x;
  if (id < 1024){
#pragma unroll
    for (int i = 0; i < 8; i++){
      int row = id * 8 + i;                 // 0..8191; blocks never straddle 4096
      const float* src; u16* dst;
      if (row < 4096){
        src = Q + (size_t)row * 1024; dst = Qb + (size_t)row * 1024;
      } else {
        int r = row - 4096;
        size_t ir = (size_t)r + (size_t)(r >> 10) * 512;   // skip rows 1024..1535 per batch
        src = K + ir * 1024; dst = Kb + (size_t)r * 1024;
      }
      const float4 v = *(const float4*)(src + t * 4);
      bf16x4 o;
      o[0] = (short)f2b(v.x); o[1] = (short)f2b(v.y);
      o[2] = (short)f2b(v.z); o[3] = (short)f2b(v.w);
      *(bf16x4*)(dst + t * 4) = o;
    }
    return;
  }
  int wid = id - 1024;               // 0..767 : 3 x 256 tiles (Wq, Wk, Wv)
  int sel = wid >> 8, local = wid & 255;
  int bx = local & 15, by = local >> 4;
  const float* in  = (sel == 0) ? Wq   : (sel == 1) ? Wk   : Wv;
  u16*         out = (sel == 0) ? Wq_t : (sel == 1) ? Wk_t : Wv_t;
  const int k0 = by * 64, n0 = bx * 64;
  const int tr = t >> 4, tc = t & 15;
#pragma unroll
  for (int i = 0; i < 4; i++){
    int r = tr + i * 16;
    float4 v = *(const float4*)(in + (size_t)(k0 + r) * 1024 + n0 + tc * 4);
    tile[r][tc*4+0] = v.x; tile[r][tc*4+1] = v.y; tile[r][tc*4+2] = v.z; tile[r][tc*4+3] = v.w;
  }
  __syncthreads();
#pragma unroll
  for (int i = 0; i < 4; i++){
    int nr = tr + i * 16;
    bf16x4 pk;
#pragma unroll
    for (int j = 0; j < 4; j++) pk[j] = (short)f2b(tile[tc*4+j][nr]);
    *(bf16x4*)(out + (size_t)(n0 + nr) * 1024 + k0 + tc * 4) = pk;
  }
}

// ---------- 256x256 8-phase main loop (T2+T3+T4+T5), BK=64, 8 waves ----------
static __device__ __forceinline__ void loop8p(const u16* __restrict__ A,
                                              const u16* __restrict__ Bt,
                                              int lda, int ldb, int kbeg, int NT,
                                              int m0, int n0,
                                              u16 (*sA)[2][8192], u16 (*sB)[2][8192],
                                              f32x4 acc[8][4]){
  const int t = threadIdx.x, w = t >> 6, l = t & 63;
  const int wr = w >> 2, wc = w & 3;
  const int c = l & 15, g = l >> 4;
  const int sr = t >> 3, scb = (t & 7) << 4;

  auto stA = [&](int d, int h, int T){
#pragma unroll
    for (int i = 0; i < 2; i++){
      int row = i * 64 + sr;
      int Lb  = scb ^ ((row & 7) << 4);
      gld_lds16(A + (size_t)(m0 + h * 128 + row) * lda + kbeg + T * 64 + (Lb >> 1),
                (char*)&sA[d][h][0] + i * 8192 + t * 16);
    }
  };
  auto stB = [&](int d, int h, int T){
#pragma unroll
    for (int i = 0; i < 2; i++){
      int row = i * 64 + sr;
      int Lb  = scb ^ ((row & 7) << 4);
      gld_lds16(Bt + (size_t)(n0 + h * 128 + row) * ldb + kbeg + T * 64 + (Lb >> 1),
                (char*)&sB[d][h][0] + i * 8192 + t * 16);
    }
  };

  // prologue: B0(0),B1(0),A0(0),A1(0),B0(1),B1(1)
  stB(0, 0, 0); stB(0, 1, 0); stA(0, 0, 0); stA(0, 1, 0);
  stB(1, 0, 1); stB(1, 1, 1);

  bf16x8 bfr[4][2];
  for (int T = 0; T < NT; ++T){
    const int d = T & 1;
    const char* pa = (const char*)&sA[d][wr][0];
    const char* pb = (const char*)&sB[d][wc >> 1][0];
#pragma unroll
    for (int q = 0; q < 4; ++q){
      if (q == 0){
        if (T + 1 < NT) asm volatile("s_waitcnt vmcnt(4)" ::: "memory");
        else            asm volatile("s_waitcnt vmcnt(0)" ::: "memory");
        asm volatile("" ::: "memory");
        __builtin_amdgcn_s_barrier();
        asm volatile("" ::: "memory");
#pragma unroll
        for (int nf = 0; nf < 4; ++nf){
          int lr = (wc & 1) * 64 + nf * 16 + c;
#pragma unroll
          for (int ks = 0; ks < 2; ++ks)
            bfr[nf][ks] = *(const bf16x8*)(pb + lr * 128 + ((ks * 64 + g * 16) ^ ((lr & 7) << 4)));
        }
      }
      bf16x8 af[2][2];
#pragma unroll
      for (int mi = 0; mi < 2; ++mi){
        int lr = (q * 2 + mi) * 16 + c;
#pragma unroll
        for (int ks = 0; ks < 2; ++ks)
          af[mi][ks] = *(const bf16x8*)(pa + lr * 128 + ((ks * 64 + g * 16) ^ ((lr & 7) << 4)));
      }
      if      (q == 0){ if (T + 1 < NT) stA(d ^ 1, 0, T + 1); }
      else if (q == 1){ if (T + 1 < NT) stA(d ^ 1, 1, T + 1); }
      else if (q == 2){ if (T + 2 < NT) stB(d, 0, T + 2); }
      else            { if (T + 2 < NT) stB(d, 1, T + 2); }
      __builtin_amdgcn_s_setprio(1);
#pragma unroll
      for (int mi = 0; mi < 2; ++mi)
#pragma unroll
        for (int nf = 0; nf < 4; ++nf)
#pragma unroll
          for (int ks = 0; ks < 2; ++ks)
            acc[q * 2 + mi][nf] =
              __builtin_amdgcn_mfma_f32_16x16x32_bf16(af[mi][ks], bfr[nf][ks], acc[q * 2 + mi][nf], 0, 0, 0);
      __builtin_amdgcn_s_setprio(0);
      asm volatile("" ::: "memory");
      __builtin_amdgcn_s_barrier();
      asm volatile("" ::: "memory");
    }
  }
}

// ---------- LDS-staged coalesced epilogue: wave's C[128x64] -> 16B row stores ----------
template<typename F>
static __device__ __forceinline__ void epi_store(char* sl, u16* gbase, int ld,
                                                 int l, F val){
  const int c = l & 15, g = l >> 4;
#pragma unroll
  for (int p = 0; p < 2; ++p){
#pragma unroll
    for (int mi = 0; mi < 4; ++mi){
#pragma unroll
      for (int nf = 0; nf < 4; ++nf){
        int col2 = (nf * 16 + c) * 2;
#pragma unroll
        for (int r = 0; r < 4; ++r){
          int row = mi * 16 + 4 * g + r;
          *(u16*)(sl + row * 128 + (col2 ^ ((row & 7) << 4))) = f2b(val(p * 4 + mi, nf, r));
        }
      }
    }
    asm volatile("s_waitcnt lgkmcnt(0)" ::: "memory");
    __builtin_amdgcn_sched_barrier(0);
#pragma unroll
    for (int j = 0; j < 8; ++j){
      int row = (l >> 3) + j * 8;
      int ch  = (l & 7) * 16;
      bf16x8 v = *(const bf16x8*)(sl + row * 128 + (ch ^ ((row & 7) << 4)));
      *(bf16x8*)(gbase + (size_t)(p * 64 + row) * ld + (l & 7) * 8) = v;
    }
    __builtin_amdgcn_sched_barrier(0);
  }
}

// ---------- 8-phase GEMM with XCD-rect swizzle ----------
// EPI 0 (FF1, grid 16x16): bias+relu -> bf16. EPI 1 (grid 4x16x4): bf16 split-K partial.
template<int EPI>
__global__ __launch_bounds__(512, 2) void gemm8p(const u16* __restrict__ A,
                                                 const u16* __restrict__ Bt,
                                                 const float* __restrict__ bias,
                                                 void* __restrict__ outp,
                                                 int lda, int ldb, int ldout,
                                                 int ksz, int NT){
  __shared__ u16 sA[2][2][8192];
  __shared__ u16 sB[2][2][8192];
  const int t = threadIdx.x, w = t >> 6, l = t & 63;
  const int wr = w >> 2, wc = w & 3;
  const int c = l & 15;

  int m0, n0, zidx;
  if (EPI == 0){
    int lid = blockIdx.x + (blockIdx.y << 4);
    int xcd = lid & 7, slot = lid >> 3;
    int bx = ((xcd & 1) << 3) + (slot & 7);
    int by = ((xcd >> 1) << 2) + (slot >> 3);
    m0 = by * 256; n0 = bx * 256; zidx = 0;
  } else {
    int lid = blockIdx.x + (blockIdx.y << 2) + (blockIdx.z << 6);
    int xcd = lid & 7, slot = lid >> 3;
    int bx = slot & 3, rest = slot >> 2;
    int by = (xcd << 1) + (rest & 1);
    zidx = rest >> 1;
    m0 = by * 256; n0 = bx * 256;
  }

  f32x4 acc[8][4];
#pragma unroll
  for (int i = 0; i < 8; i++)
#pragma unroll
    for (int j = 0; j < 4; j++) acc[i][j] = (f32x4){0.f, 0.f, 0.f, 0.f};

  loop8p(A, Bt, lda, ldb, zidx * ksz, NT, m0, n0, sA, sB, acc);

  char* slw = (char*)&sA[0][0][0] + w * 8192;        // 8KB per-wave slice
  if (EPI == 0){
    float bv[4];
#pragma unroll
    for (int nf = 0; nf < 4; ++nf) bv[nf] = bias[n0 + wc * 64 + nf * 16 + c];
    u16* gb = (u16*)outp + (size_t)(m0 + wr * 128) * ldout + n0 + wc * 64;
    epi_store(slw, gb, ldout, l,
              [&](int mf, int nf, int r){ return fmaxf(acc[mf][nf][r] + bv[nf], 0.f); });
  } else {
    u16* gb = (u16*)outp + (size_t)zidx * (4096ull * 1024ull)
              + (size_t)(m0 + wr * 128) * 1024 + n0 + wc * 64;
    epi_store(slw, gb, 1024, l,
              [&](int mf, int nf, int r){ return acc[mf][nf][r]; });
  }
}

// ---------- fused QKV (blocks 0..191: 8-phase 256² GEMM; 192..1343: Wo0/Wo/Wo2 transposes) ----------
__global__ __launch_bounds__(512, 2) void gemm8p_qkv(const u16* __restrict__ Qb,
                                                     const u16* __restrict__ Kb,
                                                     const u16* __restrict__ Wq_t,
                                                     const u16* __restrict__ Wk_t,
                                                     const u16* __restrict__ Wv_t,
                                                     const float* __restrict__ bq,
                                                     const float* __restrict__ bk,
                                                     const float* __restrict__ bv,
                                                     u16* __restrict__ qb,
                                                     u16* __restrict__ kbf,
                                                     u16* __restrict__ vtb,
                                                     const float* __restrict__ Wo0, u16* __restrict__ Wo0_t,
                                                     const float* __restrict__ Wo,  u16* __restrict__ Wo_t,
                                                     const float* __restrict__ Wo2, u16* __restrict__ Wo2_t){
  __shared__ u16 sA[2][2][8192];
  __shared__ u16 sB[2][2][8192];
  const int id = blockIdx.x, t = threadIdx.x;

  if (id >= 192){
    // ---- folded weight transposes: 2 x 64x64 tiles per 512-thread block,
    // 1152 blocks -> 2304 tiles = Wo0(256) + Wo(1024) + Wo2(1024). ----
    const int half = t >> 8, tt = t & 255;
    const int tileid = (id - 192) * 2 + half;          // 0..2303
    const float* in; u16* out; int Kd, N, bx, by;
    if (tileid < 256){
      bx = tileid & 15; by = tileid >> 4; Kd = 1024; N = 1024; in = Wo0; out = Wo0_t;
    } else if (tileid < 1280){
      int lo = tileid - 256; bx = lo & 63; by = lo >> 6; Kd = 1024; N = 4096; in = Wo; out = Wo_t;
    } else {
      int lo = tileid - 1280; bx = lo & 15; by = lo >> 4; Kd = 4096; N = 1024; in = Wo2; out = Wo2_t;
    }
    u16* tl = (u16*)&sA[0][0][0] + half * 4160;        // 64x65 u16 per half
    const int k0 = by * 64, n0 = bx * 64;
    const int tr = tt >> 4, tc = tt & 15;
#pragma unroll
    for (int i = 0; i < 4; i++){
      int r = tr + i * 16;
      float4 v = *(const float4*)(in + (size_t)(k0 + r) * N + n0 + tc * 4);
      tl[r * 65 + tc * 4 + 0] = f2b(v.x); tl[r * 65 + tc * 4 + 1] = f2b(v.y);
      tl[r * 65 + tc * 4 + 2] = f2b(v.z); tl[r * 65 + tc * 4 + 3] = f2b(v.w);
    }
    __syncthreads();
#pragma unroll
    for (int i = 0; i < 4; i++){
      int nr = tr + i * 16;
      bf16x4 pk;
#pragma unroll
      for (int j = 0; j < 4; j++) pk[j] = (short)tl[(tc * 4 + j) * 65 + nr];
      *(bf16x4*)(out + (size_t)(n0 + nr) * Kd + k0 + tc * 4) = pk;
    }
    return;
  }

  int lid = id;
  int xcd = lid & 7, slot = lid >> 3;
  int bx = (xcd & 3) * 3 + slot % 3;
  int by = ((xcd >> 2) << 3) + slot / 3;
  const int sel = bx >> 2;
  const u16* A    = sel ? Kb : Qb;
  const u16* Bt   = (sel == 0) ? Wq_t : (sel == 1) ? Wk_t : Wv_t;
  const float* bi = (sel == 0) ? bq   : (sel == 1) ? bk   : bv;
  const int w = t >> 6, l = t & 63;
  const int wr = w >> 2, wc = w & 3;
  const int c = l & 15, g = l >> 4;
  const int m0 = by * 256, n0 = (bx & 3) * 256;

  f32x4 acc[8][4];
#pragma unroll
  for (int i = 0; i < 8; i++)
#pragma unroll
    for (int j = 0; j < 4; j++) acc[i][j] = (f32x4){0.f, 0.f, 0.f, 0.f};

  loop8p(A, Bt, 1024, 1024, 0, 16, m0, n0, sA, sB, acc);

  if (sel == 2){
    // V: per-wave LDS transpose (16KB slices), then coalesced vt row stores
    u16* sl = (w < 4) ? (&sA[0][0][0] + w * 8192) : (&sB[0][0][0] + (w - 4) * 8192);
#pragma unroll
    for (int nf = 0; nf < 4; ++nf){
      int n = n0 + wc * 64 + nf * 16 + c;
      float bv_ = bi[n];
#pragma unroll
      for (int mf = 0; mf < 8; ++mf){
        bf16x4 pk;
#pragma unroll
        for (int r = 0; r < 4; ++r) pk[r] = (short)f2b(acc[mf][nf][r] + bv_);
        *(bf16x4*)(sl + (nf * 16 + c) * 128 + mf * 16 + 4 * g) = pk;
      }
    }
    asm volatile("s_waitcnt lgkmcnt(0)" ::: "memory");
    __builtin_amdgcn_sched_barrier(0);
    const int mg = m0 + wr * 128;
    const int bb = mg >> 10, kb0 = mg & 1023;
    u16* vbase = vtb + ((size_t)bb << 20) + kb0;
#pragma unroll
    for (int j = 0; j < 16; ++j){
      int nl  = (l >> 4) + j * 4;
      int kl  = (l & 15) * 8;
      bf16x8 v = *(const bf16x8*)(sl + nl * 128 + kl);
      *(bf16x8*)(vbase + (size_t)(n0 + wc * 64 + nl) * 1024 + kl) = v;
    }
  } else {
    char* slw = (char*)&sA[0][0][0] + w * 8192;
    float bv[4];
#pragma unroll
    for (int nf = 0; nf < 4; ++nf) bv[nf] = bi[n0 + wc * 64 + nf * 16 + c];
    u16* out = sel ? kbf : qb;
    u16* gb  = out + (size_t)(m0 + wr * 128) * 1024 + n0 + wc * 64;
    epi_store(slw, gb, 1024, l,
              [&](int mf, int nf, int r){ return acc[mf][nf][r] + bv[nf]; });
  }
}

// ---------- combine NP bf16 partials + bias + residual, then LayerNorm ----------
template<int NP, int F32OUT>
__global__ __launch_bounds__(256) void comb_ln(const u16* __restrict__ pp,
                                               const float* __restrict__ bias,
                                               const u16* __restrict__ res,
                                               const float* __restrict__ gw,
                                               const float* __restrict__ bw,
                                               void* __restrict__ outp){
  const int t = threadIdx.x, w = t >> 6;
  const int row = blockIdx.x * 2 + (t >> 7);
  const int u = t & 127;
  const size_t i8 = (size_t)row * 1024 + u * 8;
  bf16x8 rv = *(const bf16x8*)(res + i8);
  float4 b0 = *(const float4*)(bias + u * 8);
  float4 b1 = *(const float4*)(bias + u * 8 + 4);
  float xs[8] = {b0.x, b0.y, b0.z, b0.w, b1.x, b1.y, b1.z, b1.w};
#pragma unroll
  for (int j = 0; j < 8; j++) xs[j] += b2f((u16)rv[j]);
#pragma unroll
  for (int z = 0; z < NP; z++){
    bf16x8 p = *(const bf16x8*)(pp + (size_t)z * (4096ull * 1024ull) + i8);
#pragma unroll
    for (int j = 0; j < 8; j++) xs[j] += b2f((u16)p[j]);
  }
  float s = 0.f, sq = 0.f;
#pragma unroll
  for (int j = 0; j < 8; j++){ s += xs[j]; sq += xs[j] * xs[j]; }
#pragma unroll
  for (int o = 32; o; o >>= 1){ s += __shfl_xor(s, o); sq += __shfl_xor(sq, o); }
  __shared__ float rs[4], rq[4];
  if ((t & 63) == 0){ rs[w] = s; rq[w] = sq; }
  __syncthreads();
  const int wb = (t >> 7) * 2;
  s  = rs[wb] + rs[wb + 1];
  sq = rq[wb] + rq[wb + 1];
  const float mu   = s * (1.f / 1024.f);
  const float var  = sq * (1.f / 1024.f) - mu * mu;
  const float rstd = rsqrtf(var + 1e-5f);
  float4 g0 = *(const float4*)(gw + u * 8);
  float4 g1 = *(const float4*)(gw + u * 8 + 4);
  float4 w0 = *(const float4*)(bw + u * 8);
  float4 w1 = *(const float4*)(bw + u * 8 + 4);
  float gv[8] = {g0.x, g0.y, g0.z, g0.w, g1.x, g1.y, g1.z, g1.w};
  float wv[8] = {w0.x, w0.y, w0.z, w0.w, w1.x, w1.y, w1.z, w1.w};
  if (F32OUT){
    float4 o0, o1;
    o0.x = (xs[0]-mu)*rstd*gv[0] + wv[0]; o0.y = (xs[1]-mu)*rstd*gv[1] + wv[1];
    o0.z = (xs[2]-mu)*rstd*gv[2] + wv[2]; o0.w = (xs[3]-mu)*rstd*gv[3] + wv[3];
    o1.x = (xs[4]-mu)*rstd*gv[4] + wv[4]; o1.y = (xs[5]-mu)*rstd*gv[5] + wv[5];
    o1.z = (xs[6]-mu)*rstd*gv[6] + wv[6]; o1.w = (xs[7]-mu)*rstd*gv[7] + wv[7];
    *(float4*)((float*)outp + i8)     = o0;
    *(float4*)((float*)outp + i8 + 4) = o1;
  } else {
    bf16x8 o;
#pragma unroll
    for (int j = 0; j < 8; j++) o[j] = (short)f2b((xs[j]-mu)*rstd*gv[j] + wv[j]);
    *(bf16x8*)((u16*)outp + i8) = o;
  }
}

// ---------- fused masked attention (128 q-rows/block, 8 waves) ----------
#define ATTN_STEP(IT, CUR, MC) do{                                              \
  if ((IT) < 15) asm volatile("s_waitcnt vmcnt(4)" ::: "memory");               \
  else           asm volatile("s_waitcnt vmcnt(0)" ::: "memory");               \
  __builtin_amdgcn_s_barrier();                                                 \
  asm volatile("" ::: "memory");                                                \
  if ((IT) < 15) stage((CUR) ^ 1, ((IT) + 1) * 64);                             \
  asm volatile("" ::: "memory");                                                \
  const char* kt = (const char*)sK[(CUR)];                                      \
  f32x4 st[4];                                                                  \
  _Pragma("unroll")                                                             \
  for (int nf = 0; nf < 4; nf++){                                               \
    const char* kr = kt + (nf * 16 + c) * 128;                                  \
    bf16x8 ak0 = *(const bf16x8*)(kr + ((g * 16) ^ sw));                        \
    bf16x8 ak1 = *(const bf16x8*)(kr + ((64 + g * 16) ^ sw));                   \
    f32x4 z = (f32x4){0.f, 0.f, 0.f, 0.f};                                      \
    z = __builtin_amdgcn_mfma_f32_16x16x32_bf16(ak0, bq0, z, 0, 0, 0);          \
    z = __builtin_amdgcn_mfma_f32_16x16x32_bf16(ak1, bq1, z, 0, 0, 0);          \
    st[nf] = z;                                                                 \
  }                                                                             \
  float rsum = 0.f;                                                             \
  bf16x4 pb[4];                                                                 \
  _Pragma("unroll")                                                             \
  for (int nf = 0; nf < 4; nf++)                                                \
    _Pragma("unroll")                                                           \
    for (int r = 0; r < 4; r++){                                                \
      float p = __expf(fmaf(st[nf][r], 0.03125f, MC[nf][r]) - 8.f);             \
      rsum += p;                                                                \
      pb[nf][r] = (short)f2b(p);                                                \
    }                                                                           \
  if ((IT) < 14){                                                               \
    _Pragma("unroll")                                                           \
    for (int nf = 0; nf < 4; nf++)                                              \
      MC[nf] = *(const f32x4*)(mbase + ((IT) + 2) * 64 + nf * 16 + g * 4);      \
  }                                                                             \
  rsum += __shfl_xor(rsum, 16); rsum += __shfl_xor(rsum, 32);                   \
  lsum += rsum;                                                                 \
  const char* vtc = (const char*)sV[(CUR)];                                     \
  __builtin_amdgcn_s_setprio(1);                                                \
  _Pragma("unroll")                                                             \
  for (int f = 0; f < 4; f++){                                                  \
    const char* vr = vtc + (f * 16 + c) * 128;                                  \
    _Pragma("unroll")                                                           \
    for (int nf = 0; nf < 4; nf++){                                             \
      bf16x4 av = *(const bf16x4*)(vr + ((nf * 32 + g * 8) ^ sw));              \
      acc[f] = __builtin_amdgcn_mfma_f32_16x16x16bf16_1k(av, pb[nf], acc[f], 0, 0, 0); \
    }                                                                           \
  }                                                                             \
  __builtin_amdgcn_s_setprio(0);                                                \
}while(0)

__global__ __launch_bounds__(512, 4) void attn_k(const u16* __restrict__ qb,
                                                 const u16* __restrict__ kb,
                                                 const u16* __restrict__ vt,
                                                 const float* __restrict__ mask,
                                                 u16* __restrict__ ob){
  __shared__ u16 sK[2][4096];   // [key 64][dh 64], row stride 128B, XOR-swizzled
  __shared__ u16 sV[2][4096];   // [dh 64][key 64], row stride 128B, XOR-swizzled

  const int aid = blockIdx.x, t = threadIdx.x;
  const int w = t >> 6, l = t & 63;
  const int c = l & 15, g = l >> 4;
  const int q0 = (aid & 7) * 128;
  const int h  = (aid >> 3) & 15, b = aid >> 7;
  const int qrow = q0 + w * 16 + c;
  const size_t qoff = ((size_t)(b * 1024 + qrow)) * 1024 + h * 64;
  const bf16x8 bq0 = *(const bf16x8*)(qb + qoff + g * 8);
  const bf16x8 bq1 = *(const bf16x8*)(qb + qoff + 32 + g * 8);
  const u16* kbase = kb + ((size_t)b * 1024) * 1024 + h * 64;
  const u16* vbase = vt + ((size_t)b << 20) + (size_t)(h * 64) * 1024;
  const float* mbase = mask + ((size_t)(h * 4 + b) * 1024 + qrow) * 1024;

  const int srow = t >> 3, slc = t & 7;             // 512 threads cover 64 rows x 128B

  auto stage = [&](int buf, int kv){
    int L = (slc * 16) ^ ((srow & 7) << 4);
    gld_lds16(kbase + (size_t)(kv + srow) * 1024 + (L >> 1), &sK[buf][t * 8]);
    gld_lds16(vbase + (size_t)srow * 1024 + kv + (L >> 1),   &sV[buf][t * 8]);
  };

  float lsum = 0.f;
  f32x4 acc[4];
#pragma unroll
  for (int f = 0; f < 4; f++) acc[f] = (f32x4){0.f, 0.f, 0.f, 0.f};

  stage(0, 0);
  asm volatile("" ::: "memory");
  f32x4 mA[4], mB[4];
#pragma unroll
  for (int nf = 0; nf < 4; nf++) mA[nf] = *(const f32x4*)(mbase + nf * 16 + g * 4);
  asm volatile("" ::: "memory");
#pragma unroll
  for (int nf = 0; nf < 4; nf++) mB[nf] = *(const f32x4*)(mbase + 64 + nf * 16 + g * 4);

  const int sw = (c & 7) << 4;
  for (int ii = 0; ii < 8; ++ii){
    ATTN_STEP(2 * ii,     0, mA);
    ATTN_STEP(2 * ii + 1, 1, mB);
  }

  // epilogue: barrier, O^T -> LDS, coalesced stores
  __syncthreads();
  const float inv = 1.f / lsum;
  u16* sO = &sK[0][0];                               // [128 rows][64 dh] = 16KB = all of sK
#pragma unroll
  for (int f = 0; f < 4; f++){
    bf16x4 pk;
#pragma unroll
    for (int r = 0; r < 4; r++) pk[r] = (short)f2b(acc[f][r] * inv);
    *(bf16x4*)(sO + (w * 16 + c) * 64 + f * 16 + 4 * g) = pk;
  }
  asm volatile("s_waitcnt lgkmcnt(0)" ::: "memory");
  __builtin_amdgcn_sched_barrier(0);
  {
    int rl  = w * 16 + (l >> 2);
    int d0  = (l & 3) * 16;
    bf16x8 v0 = *(const bf16x8*)(sO + rl * 64 + d0);
    bf16x8 v1 = *(const bf16x8*)(sO + rl * 64 + d0 + 8);
    u16* dst = ob + ((size_t)(b * 1024 + q0 + rl)) * 1024 + h * 64 + d0;
    *(bf16x8*)(dst)     = v0;
    *(bf16x8*)(dst + 8) = v1;
  }
}

// ---------- launch ----------
extern "C" void kernel_launch(void* const* d_in, const int* in_sizes, int n_in,
                              void* d_out, int out_size, void* d_ws, size_t ws_size,
                              hipStream_t stream){
  const float* Q    = (const float*)d_in[0];
  const float* K    = (const float*)d_in[1];
  const float* mask = (const float*)d_in[2];
  const float* Wq   = (const float*)d_in[4];  const float* bq  = (const float*)d_in[5];
  const float* Wk   = (const float*)d_in[6];  const float* bk  = (const float*)d_in[7];
  const float* Wv   = (const float*)d_in[8];  const float* bv  = (const float*)d_in[9];
  const float* Wo0  = (const float*)d_in[10]; const float* bo0 = (const float*)d_in[11];
  const float* Wo   = (const float*)d_in[12]; const float* bo  = (const float*)d_in[13];
  const float* Wo2  = (const float*)d_in[14]; const float* bo2 = (const float*)d_in[15];
  const float* g0   = (const float*)d_in[16]; const float* be0 = (const float*)d_in[17];
  const float* g1   = (const float*)d_in[18]; const float* be1 = (const float*)d_in[19];

  uint8_t* W = (uint8_t*)d_ws;
  const size_t MB = 1024ull * 1024ull;
  u16* Wq_t  = (u16*)(W + 0);
  u16* Wk_t  = (u16*)(W + 2  * MB);
  u16* Wv_t  = (u16*)(W + 4  * MB);
  u16* Wo0_t = (u16*)(W + 6  * MB);
  u16* Wo_t  = (u16*)(W + 8  * MB);   // [4096][1024]
  u16* Wo2_t = (u16*)(W + 16 * MB);   // [1024][4096]
  u16* Qb    = (u16*)(W + 24 * MB);
  u16* Kb    = (u16*)(W + 32 * MB);
  u16* qb    = (u16*)(W + 40 * MB);
  u16* kbf   = (u16*)(W + 48 * MB);
  u16* vtb   = (u16*)(W + 56 * MB);
  u16* ob    = (u16*)(W + 24 * MB);   // reuse Qb
  u16* x1b   = (u16*)(W + 64 * MB);
  u16* hb    = (u16*)(W + 32 * MB);   // [4096][4096] bf16, spans dead Kb/qb/kbf/vtb
  u16* ppb   = (u16*)(W + 72 * MB);   // 4 x 8MB bf16 split-K partials

  // Q/K convert (8 rows/block) + QKV weight transposes
  prep<<<1792, 256, 0, stream>>>(Q, K, Qb, Kb, Wq, Wq_t, Wk, Wk_t, Wv, Wv_t);

  // fused QKV projections (192 GEMM blocks) + 1152 transpose blocks (2304 tiles)
  gemm8p_qkv<<<1344, 512, 0, stream>>>(Qb, Kb, Wq_t, Wk_t, Wv_t,
                                       bq, bk, bv, qb, kbf, vtb,
                                       Wo0, Wo0_t, Wo, Wo_t, Wo2, Wo2_t);

  // attention (pure; 512 blocks x 512 threads)
  attn_k<<<512, 512, 0, stream>>>(qb, kbf, vtb, mask, ob);

  // output proj: 8-phase split-K=4 (NT=4), bf16 partials -> fused combine+LN0
  gemm8p<1><<<dim3(4, 16, 4), 512, 0, stream>>>(ob, Wo0_t, nullptr, ppb, 1024, 1024, 1024, 256, 4);
  comb_ln<4, 0><<<2048, 256, 0, stream>>>(ppb, bo0, qb, g0, be0, x1b);

  // FFN: FF1 (8-phase, relu) -> FF2 (8-phase, split-K=4, bf16 partials) -> combine+LN1
  gemm8p<0><<<dim3(16, 16), 512, 0, stream>>>(x1b, Wo_t, bo, hb, 1024, 1024, 4096, 0, 16);
  gemm8p<1><<<dim3(4, 16, 4), 512, 0, stream>>>(hb, Wo2_t, nullptr, ppb, 4096, 4096, 1024, 1024, 16);
  comb_ln<4, 1><<<2048, 256, 0, stream>>>(ppb, bo2, x1b, g1, be1, d_out);
}